// Round 6
// baseline (142.760 us; speedup 1.0000x reference)
//
#include <hip/hip_runtime.h>

// Problem constants (B=1)
#define NQ   512
#define NKV  2562
#define CH   64
#define QB   2           // queries per attn block
#define BT   1024        // attn block threads (16 waves); grid 512 -> 2 blocks/CU
#define JH   1281        // NKV/2, rows per j-half
#define PSTRIDE 132      // per (qpair, half) partial: m0,s0,m1,s1, o0[64], o1[64]

// gemm grid partition
#define KVROWS 8
#define NKVB ((NKV + KVROWS - 1) / KVROWS)   // 321
#define QROWS 16
#define NQB (NQ / QROWS)                     // 32

#define E(a, b) __expf(-fabsf((a) - (b)))

// ---------------------------------------------------------------------------
// Kernel A: q_ = q @ Wq [512,64], kv_ = kv @ Wkv [2562,128].
// ---------------------------------------------------------------------------
__global__ __launch_bounds__(256) void gemm_qkv(
    const float* __restrict__ q, const float* __restrict__ kv,
    const float* __restrict__ Wq, const float* __restrict__ Wkv,
    float* __restrict__ qp, float* __restrict__ kvp) {
  const int tid = threadIdx.x;
  if (blockIdx.x < NKVB) {
    const int j0 = blockIdx.x * KVROWS;
    __shared__ float s_in[KVROWS][CH];
    if (tid < KVROWS * (CH / 4)) {
      int r = tid >> 4, g = tid & 15;
      int j = j0 + r;
      float4 v = (j < NKV) ? ((const float4*)(kv + (size_t)j * CH))[g]
                           : make_float4(0.f, 0.f, 0.f, 0.f);
      ((float4*)&s_in[r][0])[g] = v;
    }
    __syncthreads();
    const int r = tid >> 5;
    const int mg = (tid & 31) * 4;
    float4 acc = make_float4(0.f, 0.f, 0.f, 0.f);
#pragma unroll 16
    for (int rr = 0; rr < CH; ++rr) {
      float a = s_in[r][rr];
      float4 w = *(const float4*)(Wkv + (size_t)rr * 2 * CH + mg);
      acc.x = fmaf(a, w.x, acc.x); acc.y = fmaf(a, w.y, acc.y);
      acc.z = fmaf(a, w.z, acc.z); acc.w = fmaf(a, w.w, acc.w);
    }
    int j = j0 + r;
    if (j < NKV) *(float4*)(kvp + (size_t)j * 2 * CH + mg) = acc;
  } else {
    const int i0 = (blockIdx.x - NKVB) * QROWS;
    __shared__ float s_in[QROWS][CH];
    {
      int r = tid >> 4, g = tid & 15;
      float4 v = ((const float4*)(q + (size_t)(i0 + r) * CH))[g];
      ((float4*)&s_in[r][0])[g] = v;
    }
    __syncthreads();
    const int r = tid >> 4;
    const int cg = (tid & 15) * 4;
    float4 acc = make_float4(0.f, 0.f, 0.f, 0.f);
#pragma unroll 16
    for (int rr = 0; rr < CH; ++rr) {
      float a = s_in[r][rr];
      float4 w = *(const float4*)(Wq + (size_t)rr * CH + cg);
      acc.x = fmaf(a, w.x, acc.x); acc.y = fmaf(a, w.y, acc.y);
      acc.z = fmaf(a, w.z, acc.z); acc.w = fmaf(a, w.w, acc.w);
    }
    *(float4*)(qp + (size_t)(i0 + r) * CH + cg) = acc;
  }
}

// ---------------------------------------------------------------------------
// Kernel B1: partial attention. Block = (qpair, j-half); grid 512 = 2/CU.
// Emits per query: running max m, sum s = sum exp(score-m), unnormalized
// o[c] = sum exp(score-m) * v[j,c] over its 1281-row half.
// ---------------------------------------------------------------------------
__global__ __launch_bounds__(BT, 8) void attn_part(
    const float* __restrict__ qp, const float* __restrict__ kvp,
    const float* __restrict__ qc, const float* __restrict__ kvc,
    const float* __restrict__ Wdelta, float* __restrict__ part) {
  __shared__ float s_score[QB][JH];    // 10248 B
  __shared__ float s_red[QB][BT];      // 8192 B
  __shared__ float s_wd[3];

  const int qpair = blockIdx.x >> 1;
  const int h = blockIdx.x & 1;
  const int i0 = qpair * QB;
  const int jlo = h * JH, jhi = jlo + JH;

  const int tid = threadIdx.x;
  const int sub = tid & 3;
  const int c0 = sub * 16;
  const int wid = tid >> 6;
  const int lane = tid & 63;

  if (tid < 3) {
    float s = 0.f;
    for (int c = 0; c < CH; ++c) s += Wdelta[tid * CH + c];
    s_wd[tid] = s;
  }

  // q slices into named registers (pinned)
  const float4* q0p = (const float4*)(qp + (size_t)i0 * CH + c0);
  const float4* q1p = (const float4*)(qp + (size_t)(i0 + 1) * CH + c0);
  float4 qa0 = q0p[0], qa1 = q0p[1], qa2 = q0p[2], qa3 = q0p[3];
  float4 qb0 = q1p[0], qb1 = q1p[1], qb2 = q1p[2], qb3 = q1p[3];
  asm volatile("" : "+v"(qa0.x), "+v"(qa0.y), "+v"(qa0.z), "+v"(qa0.w),
                    "+v"(qa1.x), "+v"(qa1.y), "+v"(qa1.z), "+v"(qa1.w),
                    "+v"(qa2.x), "+v"(qa2.y), "+v"(qa2.z), "+v"(qa2.w),
                    "+v"(qa3.x), "+v"(qa3.y), "+v"(qa3.z), "+v"(qa3.w));
  asm volatile("" : "+v"(qb0.x), "+v"(qb0.y), "+v"(qb0.z), "+v"(qb0.w),
                    "+v"(qb1.x), "+v"(qb1.y), "+v"(qb1.z), "+v"(qb1.w),
                    "+v"(qb2.x), "+v"(qb2.y), "+v"(qb2.z), "+v"(qb2.w),
                    "+v"(qb3.x), "+v"(qb3.y), "+v"(qb3.z), "+v"(qb3.w));

  float qc0[3], qc1[3];
#pragma unroll
  for (int d = 0; d < 3; ++d) {
    qc0[d] = qc[(size_t)i0 * 3 + d];
    qc1[d] = qc[(size_t)(i0 + 1) * 3 + d];
  }
  __syncthreads();
  const float wd0 = s_wd[0], wd1 = s_wd[1], wd2 = s_wd[2];
  const float scale = 1.0f / 64.0f;

  // ---- phase 1: scores over [jlo, jhi) ----
  float lmax0 = -1e30f, lmax1 = -1e30f;
  for (int j = jlo + (tid >> 2); j < jhi; j += BT / 4) {
    const float4* kr = (const float4*)(kvp + (size_t)j * 2 * CH + c0);
    float4 k0 = kr[0], k1 = kr[1], k2 = kr[2], k3 = kr[3];
    float s0 = ((E(qa0.x, k0.x) + E(qa0.y, k0.y)) + (E(qa0.z, k0.z) + E(qa0.w, k0.w)))
             + ((E(qa1.x, k1.x) + E(qa1.y, k1.y)) + (E(qa1.z, k1.z) + E(qa1.w, k1.w)))
             + ((E(qa2.x, k2.x) + E(qa2.y, k2.y)) + (E(qa2.z, k2.z) + E(qa2.w, k2.w)))
             + ((E(qa3.x, k3.x) + E(qa3.y, k3.y)) + (E(qa3.z, k3.z) + E(qa3.w, k3.w)));
    float s1 = ((E(qb0.x, k0.x) + E(qb0.y, k0.y)) + (E(qb0.z, k0.z) + E(qb0.w, k0.w)))
             + ((E(qb1.x, k1.x) + E(qb1.y, k1.y)) + (E(qb1.z, k1.z) + E(qb1.w, k1.w)))
             + ((E(qb2.x, k2.x) + E(qb2.y, k2.y)) + (E(qb2.z, k2.z) + E(qb2.w, k2.w)))
             + ((E(qb3.x, k3.x) + E(qb3.y, k3.y)) + (E(qb3.z, k3.z) + E(qb3.w, k3.w)));
    s0 += __shfl_xor(s0, 1); s0 += __shfl_xor(s0, 2);
    s1 += __shfl_xor(s1, 1); s1 += __shfl_xor(s1, 2);
    if (sub == 0) {
      float d0 = kvc[(size_t)j * 3 + 0], d1 = kvc[(size_t)j * 3 + 1], d2 = kvc[(size_t)j * 3 + 2];
      s0 += E(qc0[0], d0) * wd0 + E(qc0[1], d1) * wd1 + E(qc0[2], d2) * wd2;
      s1 += E(qc1[0], d0) * wd0 + E(qc1[1], d1) * wd1 + E(qc1[2], d2) * wd2;
      s0 *= scale; s1 *= scale;
      s_score[0][j - jlo] = s0; s_score[1][j - jlo] = s1;
      lmax0 = fmaxf(lmax0, s0); lmax1 = fmaxf(lmax1, s1);
    }
  }

  // ---- max: wave shfl reduce + cross-wave combine ----
#pragma unroll
  for (int off = 1; off < 64; off <<= 1) {
    lmax0 = fmaxf(lmax0, __shfl_xor(lmax0, off));
    lmax1 = fmaxf(lmax1, __shfl_xor(lmax1, off));
  }
  if (lane == 0) { s_red[0][wid] = lmax0; s_red[1][wid] = lmax1; }
  __syncthreads();
  float m0 = s_red[0][0], m1 = s_red[1][0];
#pragma unroll
  for (int w = 1; w < BT / 64; ++w) {
    m0 = fmaxf(m0, s_red[0][w]);
    m1 = fmaxf(m1, s_red[1][w]);
  }
  __syncthreads();

  // ---- exp + sum ----
  float ls0 = 0.f, ls1 = 0.f;
  for (int jj = tid; jj < JH; jj += BT) {
    float p0 = __expf(s_score[0][jj] - m0); s_score[0][jj] = p0; ls0 += p0;
    float p1 = __expf(s_score[1][jj] - m1); s_score[1][jj] = p1; ls1 += p1;
  }
#pragma unroll
  for (int off = 1; off < 64; off <<= 1) {
    ls0 += __shfl_xor(ls0, off);
    ls1 += __shfl_xor(ls1, off);
  }
  if (lane == 0) { s_red[0][wid] = ls0; s_red[1][wid] = ls1; }
  __syncthreads();
  float t0 = s_red[0][0], t1 = s_red[1][0];
#pragma unroll
  for (int w = 1; w < BT / 64; ++w) { t0 += s_red[0][w]; t1 += s_red[1][w]; }
  __syncthreads();

  // ---- phase 2: unnormalized o[c] = sum_j p_j * v[j,c] ----
  const int c = tid & 63, g = tid >> 6;
  float a0 = 0.f, a1 = 0.f;
#pragma unroll 4
  for (int j = jlo + g; j < jhi; j += 16) {
    float v = kvp[(size_t)j * 128 + 64 + c];
    a0 = fmaf(s_score[0][j - jlo], v, a0);
    a1 = fmaf(s_score[1][j - jlo], v, a1);
  }
  s_red[0][tid] = a0; s_red[1][tid] = a1;
  __syncthreads();

  float* P = part + (size_t)(qpair * 2 + h) * PSTRIDE;
  if (g == 0) {
    float u0 = 0.f, u1 = 0.f;
#pragma unroll
    for (int gg = 0; gg < 16; ++gg) {
      u0 += s_red[0][gg * 64 + c];
      u1 += s_red[1][gg * 64 + c];
    }
    P[4 + c] = u0;
    P[68 + c] = u1;
    if (c == 0) { P[0] = m0; P[1] = t0; P[2] = m1; P[3] = t1; }
  }
}

// ---------------------------------------------------------------------------
// Kernel B2: merge halves + projection. Block = 4 queries x 64 channels.
// ---------------------------------------------------------------------------
__global__ __launch_bounds__(256) void attn_merge(
    const float* __restrict__ part, const float* __restrict__ Wproj,
    const float* __restrict__ bproj, float* __restrict__ out) {
  __shared__ float s_o[4][CH];
  const int tid = threadIdx.x;
  const int g = tid >> 6, c = tid & 63;
  const int i = blockIdx.x * 4 + g;
  const int qp = i >> 1, qs = i & 1;

  const float* P0 = part + (size_t)(qp * 2 + 0) * PSTRIDE;
  const float* P1 = part + (size_t)(qp * 2 + 1) * PSTRIDE;
  const float m_0 = P0[2 * qs], s_0 = P0[2 * qs + 1];
  const float m_1 = P1[2 * qs], s_1 = P1[2 * qs + 1];
  const float o_0 = P0[4 + qs * 64 + c];
  const float o_1 = P1[4 + qs * 64 + c];

  const float m = fmaxf(m_0, m_1);
  const float w0 = __expf(m_0 - m), w1 = __expf(m_1 - m);
  const float inv = 1.0f / (w0 * s_0 + w1 * s_1);
  s_o[g][c] = (w0 * o_0 + w1 * o_1) * inv;
  __syncthreads();

  float acc = 0.f;
#pragma unroll 16
  for (int r = 0; r < CH; ++r)
    acc = fmaf(s_o[g][r], Wproj[r * CH + c], acc);
  out[(size_t)i * CH + c] = acc + bproj[c];
}

// ---------------------------------------------------------------------------
extern "C" void kernel_launch(void* const* d_in, const int* in_sizes, int n_in,
                              void* d_out, int out_size, void* d_ws, size_t ws_size,
                              hipStream_t stream) {
  const float* q      = (const float*)d_in[0];
  const float* qc     = (const float*)d_in[1];
  const float* kv     = (const float*)d_in[2];
  const float* kvc    = (const float*)d_in[3];
  const float* Wq     = (const float*)d_in[4];
  const float* Wkv    = (const float*)d_in[5];
  const float* Wdelta = (const float*)d_in[6];
  const float* Wproj  = (const float*)d_in[7];
  const float* bproj  = (const float*)d_in[8];
  float* outp = (float*)d_out;

  float* qp   = (float*)d_ws;                          // 512*64
  float* kvp  = qp + NQ * CH;                          // 2562*128
  float* part = kvp + (size_t)NKV * 2 * CH;            // 256*2*132 floats

  gemm_qkv<<<NKVB + NQB, 256, 0, stream>>>(q, kv, Wq, Wkv, qp, kvp);
  attn_part<<<(NQ / QB) * 2, BT, 0, stream>>>(qp, kvp, qc, kvc, Wdelta, part);
  attn_merge<<<NQ / 4, 256, 0, stream>>>(part, Wproj, bproj, outp);
}

// Round 7
// 113.209 us; speedup vs baseline: 1.2610x; 1.2610x over previous
//
#include <hip/hip_runtime.h>

// Problem constants (B=1)
#define NQ   512
#define NKV  2562
#define CH   64
#define QB   2           // queries per attn block
#define BT   1024        // attn block threads (16 waves); grid 512 -> 2 blocks/CU
#define JH   1281        // NKV/2, rows per j-half
#define PSTRIDE 132      // per (qpair, half) partial: s0,s1,pad,pad, o0[64], o1[64]

// gemm grid partition
#define KVROWS 8
#define NKVB ((NKV + KVROWS - 1) / KVROWS)   // 321
#define QROWS 16
#define NQB (NQ / QROWS)                     // 32

#define E(a, b) __expf(-fabsf((a) - (b)))

// ---------------------------------------------------------------------------
// Kernel A: q_ = q @ Wq [512,64], kv_ = kv @ Wkv [2562,128].
// ---------------------------------------------------------------------------
__global__ __launch_bounds__(256) void gemm_qkv(
    const float* __restrict__ q, const float* __restrict__ kv,
    const float* __restrict__ Wq, const float* __restrict__ Wkv,
    float* __restrict__ qp, float* __restrict__ kvp) {
  const int tid = threadIdx.x;
  if (blockIdx.x < NKVB) {
    const int j0 = blockIdx.x * KVROWS;
    __shared__ float s_in[KVROWS][CH];
    if (tid < KVROWS * (CH / 4)) {
      int r = tid >> 4, g = tid & 15;
      int j = j0 + r;
      float4 v = (j < NKV) ? ((const float4*)(kv + (size_t)j * CH))[g]
                           : make_float4(0.f, 0.f, 0.f, 0.f);
      ((float4*)&s_in[r][0])[g] = v;
    }
    __syncthreads();
    const int r = tid >> 5;
    const int mg = (tid & 31) * 4;
    float4 acc = make_float4(0.f, 0.f, 0.f, 0.f);
#pragma unroll 16
    for (int rr = 0; rr < CH; ++rr) {
      float a = s_in[r][rr];
      float4 w = *(const float4*)(Wkv + (size_t)rr * 2 * CH + mg);
      acc.x = fmaf(a, w.x, acc.x); acc.y = fmaf(a, w.y, acc.y);
      acc.z = fmaf(a, w.z, acc.z); acc.w = fmaf(a, w.w, acc.w);
    }
    int j = j0 + r;
    if (j < NKV) *(float4*)(kvp + (size_t)j * 2 * CH + mg) = acc;
  } else {
    const int i0 = (blockIdx.x - NKVB) * QROWS;
    __shared__ float s_in[QROWS][CH];
    {
      int r = tid >> 4, g = tid & 15;
      float4 v = ((const float4*)(q + (size_t)(i0 + r) * CH))[g];
      ((float4*)&s_in[r][0])[g] = v;
    }
    __syncthreads();
    const int r = tid >> 4;
    const int cg = (tid & 15) * 4;
    float4 acc = make_float4(0.f, 0.f, 0.f, 0.f);
#pragma unroll 16
    for (int rr = 0; rr < CH; ++rr) {
      float a = s_in[r][rr];
      float4 w = *(const float4*)(Wq + (size_t)rr * CH + cg);
      acc.x = fmaf(a, w.x, acc.x); acc.y = fmaf(a, w.y, acc.y);
      acc.z = fmaf(a, w.z, acc.z); acc.w = fmaf(a, w.w, acc.w);
    }
    *(float4*)(qp + (size_t)(i0 + r) * CH + cg) = acc;
  }
}

// ---------------------------------------------------------------------------
// Kernel B1: partial attention, single-pass (no max subtraction — scores are
// bounded in ~[-1,2] since each exp term is in (0,1] and scale=1/64).
// Block = (qpair, j-half); grid 512 = 2 blocks/CU (VGPR<=64, LDS 19KB).
// Emits per query: s = sum exp(score), o[c] = sum exp(score) * v[j,c].
// ---------------------------------------------------------------------------
__global__ __launch_bounds__(BT, 4) void attn_part(
    const float* __restrict__ qp, const float* __restrict__ kvp,
    const float* __restrict__ qc, const float* __restrict__ kvc,
    const float* __restrict__ Wdelta, float* __restrict__ part) {
  __shared__ float s_score[QB][JH];    // 10248 B
  __shared__ float s_red[QB][BT];      // 8192 B
  __shared__ float s_wd[3];

  const int qpair = blockIdx.x >> 1;
  const int h = blockIdx.x & 1;
  const int i0 = qpair * QB;
  const int jlo = h * JH, jhi = jlo + JH;

  const int tid = threadIdx.x;
  const int sub = tid & 3;
  const int c0 = sub * 16;
  const int wid = tid >> 6;
  const int lane = tid & 63;

  if (tid < 3) {
    float s = 0.f;
    for (int c = 0; c < CH; ++c) s += Wdelta[tid * CH + c];
    s_wd[tid] = s;
  }

  // q slices into named registers (pinned so loads can't sink into the loop)
  const float4* q0p = (const float4*)(qp + (size_t)i0 * CH + c0);
  const float4* q1p = (const float4*)(qp + (size_t)(i0 + 1) * CH + c0);
  float4 qa0 = q0p[0], qa1 = q0p[1], qa2 = q0p[2], qa3 = q0p[3];
  float4 qb0 = q1p[0], qb1 = q1p[1], qb2 = q1p[2], qb3 = q1p[3];
  asm volatile("" : "+v"(qa0.x), "+v"(qa0.y), "+v"(qa0.z), "+v"(qa0.w),
                    "+v"(qa1.x), "+v"(qa1.y), "+v"(qa1.z), "+v"(qa1.w),
                    "+v"(qa2.x), "+v"(qa2.y), "+v"(qa2.z), "+v"(qa2.w),
                    "+v"(qa3.x), "+v"(qa3.y), "+v"(qa3.z), "+v"(qa3.w));
  asm volatile("" : "+v"(qb0.x), "+v"(qb0.y), "+v"(qb0.z), "+v"(qb0.w),
                    "+v"(qb1.x), "+v"(qb1.y), "+v"(qb1.z), "+v"(qb1.w),
                    "+v"(qb2.x), "+v"(qb2.y), "+v"(qb2.z), "+v"(qb2.w),
                    "+v"(qb3.x), "+v"(qb3.y), "+v"(qb3.z), "+v"(qb3.w));

  float qc0[3], qc1[3];
#pragma unroll
  for (int d = 0; d < 3; ++d) {
    qc0[d] = qc[(size_t)i0 * 3 + d];
    qc1[d] = qc[(size_t)(i0 + 1) * 3 + d];
  }
  __syncthreads();
  const float wd0 = s_wd[0], wd1 = s_wd[1], wd2 = s_wd[2];
  const float scale = 1.0f / 64.0f;

  // ---- phase 1: p = exp(score) over [jlo, jhi), fused running sum ----
  float ls0 = 0.f, ls1 = 0.f;
  for (int j = jlo + (tid >> 2); j < jhi; j += BT / 4) {
    const float4* kr = (const float4*)(kvp + (size_t)j * 2 * CH + c0);
    float4 k0 = kr[0], k1 = kr[1], k2 = kr[2], k3 = kr[3];
    float s0 = ((E(qa0.x, k0.x) + E(qa0.y, k0.y)) + (E(qa0.z, k0.z) + E(qa0.w, k0.w)))
             + ((E(qa1.x, k1.x) + E(qa1.y, k1.y)) + (E(qa1.z, k1.z) + E(qa1.w, k1.w)))
             + ((E(qa2.x, k2.x) + E(qa2.y, k2.y)) + (E(qa2.z, k2.z) + E(qa2.w, k2.w)))
             + ((E(qa3.x, k3.x) + E(qa3.y, k3.y)) + (E(qa3.z, k3.z) + E(qa3.w, k3.w)));
    float s1 = ((E(qb0.x, k0.x) + E(qb0.y, k0.y)) + (E(qb0.z, k0.z) + E(qb0.w, k0.w)))
             + ((E(qb1.x, k1.x) + E(qb1.y, k1.y)) + (E(qb1.z, k1.z) + E(qb1.w, k1.w)))
             + ((E(qb2.x, k2.x) + E(qb2.y, k2.y)) + (E(qb2.z, k2.z) + E(qb2.w, k2.w)))
             + ((E(qb3.x, k3.x) + E(qb3.y, k3.y)) + (E(qb3.z, k3.z) + E(qb3.w, k3.w)));
    s0 += __shfl_xor(s0, 1); s0 += __shfl_xor(s0, 2);
    s1 += __shfl_xor(s1, 1); s1 += __shfl_xor(s1, 2);
    if (sub == 0) {
      float d0 = kvc[(size_t)j * 3 + 0], d1 = kvc[(size_t)j * 3 + 1], d2 = kvc[(size_t)j * 3 + 2];
      s0 += E(qc0[0], d0) * wd0 + E(qc0[1], d1) * wd1 + E(qc0[2], d2) * wd2;
      s1 += E(qc1[0], d0) * wd0 + E(qc1[1], d1) * wd1 + E(qc1[2], d2) * wd2;
      float p0 = __expf(s0 * scale);
      float p1 = __expf(s1 * scale);
      s_score[0][j - jlo] = p0; s_score[1][j - jlo] = p1;
      ls0 += p0; ls1 += p1;
    }
  }

  // ---- sum: wave shfl reduce + cross-wave combine ----
#pragma unroll
  for (int off = 1; off < 64; off <<= 1) {
    ls0 += __shfl_xor(ls0, off);
    ls1 += __shfl_xor(ls1, off);
  }
  if (lane == 0) { s_red[0][wid] = ls0; s_red[1][wid] = ls1; }
  __syncthreads();
  float t0 = s_red[0][0], t1 = s_red[1][0];
#pragma unroll
  for (int w = 1; w < BT / 64; ++w) { t0 += s_red[0][w]; t1 += s_red[1][w]; }
  __syncthreads();   // done reading s_red before reuse; s_score visible

  // ---- phase 2: unnormalized o[c] = sum_j p_j * v[j,c] ----
  const int c = tid & 63, g = tid >> 6;
  float a0 = 0.f, a1 = 0.f;
#pragma unroll 4
  for (int j = jlo + g; j < jhi; j += 16) {
    float v = kvp[(size_t)j * 128 + 64 + c];
    a0 = fmaf(s_score[0][j - jlo], v, a0);
    a1 = fmaf(s_score[1][j - jlo], v, a1);
  }
  s_red[0][tid] = a0; s_red[1][tid] = a1;
  __syncthreads();

  float* P = part + (size_t)(qpair * 2 + h) * PSTRIDE;
  if (g == 0) {
    float u0 = 0.f, u1 = 0.f;
#pragma unroll
    for (int gg = 0; gg < 16; ++gg) {
      u0 += s_red[0][gg * 64 + c];
      u1 += s_red[1][gg * 64 + c];
    }
    P[4 + c] = u0;
    P[68 + c] = u1;
    if (c == 0) { P[0] = t0; P[1] = t1; P[2] = 0.f; P[3] = 0.f; }
  }
}

// ---------------------------------------------------------------------------
// Kernel B2: merge halves + projection. Block = 4 queries x 64 channels.
// No max terms: out_unnorm = (o_h0 + o_h1) / (s_h0 + s_h1).
// ---------------------------------------------------------------------------
__global__ __launch_bounds__(256) void attn_merge(
    const float* __restrict__ part, const float* __restrict__ Wproj,
    const float* __restrict__ bproj, float* __restrict__ out) {
  __shared__ float s_o[4][CH];
  const int tid = threadIdx.x;
  const int g = tid >> 6, c = tid & 63;
  const int i = blockIdx.x * 4 + g;
  const int qp = i >> 1, qs = i & 1;

  const float* P0 = part + (size_t)(qp * 2 + 0) * PSTRIDE;
  const float* P1 = part + (size_t)(qp * 2 + 1) * PSTRIDE;
  const float s_0 = P0[qs], s_1 = P1[qs];
  const float o_0 = P0[4 + qs * 64 + c];
  const float o_1 = P1[4 + qs * 64 + c];

  const float inv = 1.0f / (s_0 + s_1);
  s_o[g][c] = (o_0 + o_1) * inv;
  __syncthreads();

  float acc = 0.f;
#pragma unroll 16
  for (int r = 0; r < CH; ++r)
    acc = fmaf(s_o[g][r], Wproj[r * CH + c], acc);
  out[(size_t)i * CH + c] = acc + bproj[c];
}

// ---------------------------------------------------------------------------
extern "C" void kernel_launch(void* const* d_in, const int* in_sizes, int n_in,
                              void* d_out, int out_size, void* d_ws, size_t ws_size,
                              hipStream_t stream) {
  const float* q      = (const float*)d_in[0];
  const float* qc     = (const float*)d_in[1];
  const float* kv     = (const float*)d_in[2];
  const float* kvc    = (const float*)d_in[3];
  const float* Wq     = (const float*)d_in[4];
  const float* Wkv    = (const float*)d_in[5];
  const float* Wdelta = (const float*)d_in[6];
  const float* Wproj  = (const float*)d_in[7];
  const float* bproj  = (const float*)d_in[8];
  float* outp = (float*)d_out;

  float* qp   = (float*)d_ws;                          // 512*64
  float* kvp  = qp + NQ * CH;                          // 2562*128
  float* part = kvp + (size_t)NKV * 2 * CH;            // 256*2*132 floats

  gemm_qkv<<<NKVB + NQB, 256, 0, stream>>>(q, kv, Wq, Wkv, qp, kvp);
  attn_part<<<(NQ / QB) * 2, BT, 0, stream>>>(qp, kvp, qc, kvc, Wdelta, part);
  attn_merge<<<NQ / 4, 256, 0, stream>>>(part, Wproj, bproj, outp);
}